// Round 1
// baseline (2899.912 us; speedup 1.0000x reference)
//
#include <hip/hip_runtime.h>
#include <stdint.h>

namespace {
constexpr int kB = 64, kT = 4096, kDin = 64, kDe = 24, kH = 128;
constexpr int kP = (kDe + kH) / 2;   // 76 half2 pairs in z = [e(24); h(128)]
constexpr float kLog2e = 1.4426950408889634f;

typedef __attribute__((ext_vector_type(2))) _Float16 half2_t;
union H2U { uint32_t u; half2_t h; _Float16 s[2]; };

__device__ __forceinline__ float rcp_fast(float x){
#if __has_builtin(__builtin_amdgcn_rcpf)
  return __builtin_amdgcn_rcpf(x);
#else
  return 1.0f / x;
#endif
}
__device__ __forceinline__ float sigmoid_f(float x){
  return rcp_fast(1.0f + __expf(-x));
}
__device__ __forceinline__ float tanh_f(float x){
  // 1 - 2/(e^{2x}+1); saturates correctly at +-1
  return 1.0f - 2.0f * rcp_fast(1.0f + __expf(2.0f * x));
}
__device__ __forceinline__ float dot2acc(uint32_t a, uint32_t b, float c){
  H2U ua; ua.u = a; H2U ub; ub.u = b;
#if __has_builtin(__builtin_amdgcn_fdot2)
  return __builtin_amdgcn_fdot2(ua.h, ub.h, c, false);
#else
  return c + (float)ua.s[0] * (float)ub.s[0] + (float)ua.s[1] * (float)ub.s[1];
#endif
}
__device__ __forceinline__ uint32_t pack2(float lo, float hi){
  H2U u; u.s[0] = (_Float16)lo; u.s[1] = (_Float16)hi; return u.u;
}
} // namespace

// Kernel 1 (parallel): e[b,t,:] = sigmoid(x[b,t,:] @ W_emb + b_emb), stored as
// 12 packed-f16-pair uints per (b,t) row in workspace.
__global__ __launch_bounds__(256) void emb_kernel(
    const float* __restrict__ x,      // [B*T, 64]
    const float* __restrict__ W,      // [64, 24]
    const float* __restrict__ bias,   // [24]
    uint32_t* __restrict__ e_out)     // [B*T, 12]
{
  int r = blockIdx.x * blockDim.x + threadIdx.x;
  if (r >= kB * kT) return;
  const float4* xr = (const float4*)(x + (size_t)r * kDin);
  float acc[kDe];
#pragma unroll
  for (int k = 0; k < kDe; ++k) acc[k] = bias[k];
#pragma unroll 4
  for (int d4 = 0; d4 < kDin / 4; ++d4){
    float4 xv = xr[d4];
    const float* w0 = W + (size_t)(d4 * 4) * kDe;
#pragma unroll
    for (int k = 0; k < kDe; ++k) acc[k] += xv.x * w0[k];
#pragma unroll
    for (int k = 0; k < kDe; ++k) acc[k] += xv.y * w0[kDe + k];
#pragma unroll
    for (int k = 0; k < kDe; ++k) acc[k] += xv.z * w0[2 * kDe + k];
#pragma unroll
    for (int k = 0; k < kDe; ++k) acc[k] += xv.w * w0[3 * kDe + k];
  }
  uint32_t p[12];
#pragma unroll
  for (int k = 0; k < 12; ++k)
    p[k] = pack2(sigmoid_f(acc[2 * k]), sigmoid_f(acc[2 * k + 1]));
  uint4* dst = (uint4*)(e_out + (size_t)r * 12);
  dst[0] = make_uint4(p[0], p[1], p[2],  p[3]);
  dst[1] = make_uint4(p[4], p[5], p[6],  p[7]);
  dst[2] = make_uint4(p[8], p[9], p[10], p[11]);
}

// Kernel 2 (serial chain): one block per batch element, 256 threads.
// Thread t owns gate-output columns gj=t and gj=t+256 of [Wf|Wi|Wc|Wo] (512 cols),
// weights packed f16 in VGPRs. z=[e_t;h_t] as f16 in double-buffered LDS.
__global__ __launch_bounds__(256, 1) void lstm_kernel(
    const uint32_t* __restrict__ e_ws,
    const float* __restrict__ W_f, const float* __restrict__ b_f,
    const float* __restrict__ W_i, const float* __restrict__ b_i,
    const float* __restrict__ W_c, const float* __restrict__ b_c,
    const float* __restrict__ W_o, const float* __restrict__ b_o,
    const float* __restrict__ W_out, const float* __restrict__ b_out,
    float* __restrict__ out)
{
  __shared__ __align__(16) uint32_t zbuf[2][80];  // 76 used: e pairs [0,12), h pairs [12,76)
  __shared__ float gates[512];
  __shared__ float red[2];

  const int b  = blockIdx.x;
  const int t0 = threadIdx.x;      // 0..255
  const int j  = t0 & 127;

  const float* Wg0 = (t0 < 128) ? W_f : W_i;   // gate 0/1 (f,i)
  const float* Wg1 = (t0 < 128) ? W_c : W_o;   // gate 2/3 (g,o)
  const float bias0 = ((t0 < 128) ? b_f : b_i)[j];
  const float bias1 = ((t0 < 128) ? b_c : b_o)[j];

  // Pack this thread's two weight columns into f16 pairs in registers.
  uint32_t w0[kP], w1[kP];
#pragma unroll
  for (int k = 0; k < kP; ++k){
    w0[k] = pack2(Wg0[(2 * k) * kH + j], Wg0[(2 * k + 1) * kH + j]);
    w1[k] = pack2(Wg1[(2 * k) * kH + j], Wg1[(2 * k + 1) * kH + j]);
  }

  const uint4* e_rows = (const uint4*)e_ws;   // 3 uint4 per (b,t) row
  if (t0 < 3) ((uint4*)&zbuf[0][0])[t0] = e_rows[(size_t)(b * kT) * 3 + t0];
  if (t0 < 64) zbuf[0][12 + t0] = 0u;         // h = 0
  float c = 0.0f, h_last = 0.0f;
  __syncthreads();

  for (int t = 0; t < kT; ++t){
    const int cur = t & 1, nxt = cur ^ 1;
    // prefetch e[t+1] (global, consumed after the dot phase)
    uint4 epre;
    if (t0 < 3){
      int tn = (t + 1 < kT) ? (t + 1) : (kT - 1);
      epre = e_rows[(size_t)(b * kT + tn) * 3 + t0];
    }
    // phase 1: two 152-wide dots per thread (f16 dot2, f32 accumulate)
    float a0 = bias0, a1 = bias1;
    const uint4* zq = (const uint4*)&zbuf[cur][0];
#pragma unroll
    for (int r = 0; r < 19; ++r){
      uint4 q = zq[r];
      a0 = dot2acc(q.x, w0[4 * r + 0], a0);  a1 = dot2acc(q.x, w1[4 * r + 0], a1);
      a0 = dot2acc(q.y, w0[4 * r + 1], a0);  a1 = dot2acc(q.y, w1[4 * r + 1], a1);
      a0 = dot2acc(q.z, w0[4 * r + 2], a0);  a1 = dot2acc(q.z, w1[4 * r + 2], a1);
      a0 = dot2acc(q.w, w0[4 * r + 3], a0);  a1 = dot2acc(q.w, w1[4 * r + 3], a1);
    }
    gates[t0]       = a0;
    gates[t0 + 256] = a1;
    __syncthreads();
    // phase 2: per-hidden-unit gate combine + state update (threads 0..127)
    if (t0 < 128){
      float f  = sigmoid_f(gates[j]);
      float ig = sigmoid_f(gates[128 + j]);
      float gg = tanh_f(gates[256 + j]);
      float og = sigmoid_f(gates[384 + j]);
      c = c * f + ig * gg;
      h_last = tanh_f(c) * og;
      ((_Float16*)&zbuf[nxt][0])[24 + j] = (_Float16)h_last;
      if (t0 < 3) ((uint4*)&zbuf[nxt][0])[t0] = epre;
    }
    __syncthreads();
  }

  // epilogue: out[b] = sigmoid(h_T @ W_out + b_out)
  float partial = (t0 < 128) ? h_last * W_out[j] : 0.0f;
#pragma unroll
  for (int off = 32; off >= 1; off >>= 1) partial += __shfl_down(partial, off, 64);
  if (t0 == 0)  red[0] = partial;
  if (t0 == 64) red[1] = partial;
  __syncthreads();
  if (t0 == 0) out[b] = sigmoid_f(red[0] + red[1] + b_out[0]);
}

extern "C" void kernel_launch(void* const* d_in, const int* in_sizes, int n_in,
                              void* d_out, int out_size, void* d_ws, size_t ws_size,
                              hipStream_t stream){
  const float* x     = (const float*)d_in[0];
  const float* W_emb = (const float*)d_in[1];
  const float* b_emb = (const float*)d_in[2];
  const float* W_f   = (const float*)d_in[3];
  const float* b_f   = (const float*)d_in[4];
  const float* W_i   = (const float*)d_in[5];
  const float* b_i   = (const float*)d_in[6];
  const float* W_c   = (const float*)d_in[7];
  const float* b_c   = (const float*)d_in[8];
  const float* W_o   = (const float*)d_in[9];
  const float* b_o   = (const float*)d_in[10];
  const float* W_out = (const float*)d_in[11];
  const float* b_out = (const float*)d_in[12];
  float* out = (float*)d_out;
  uint32_t* e_ws = (uint32_t*)d_ws;    // needs B*T*12*4 = 12.6 MB

  const int rows = kB * kT;
  emb_kernel<<<(rows + 255) / 256, 256, 0, stream>>>(x, W_emb, b_emb, e_ws);
  lstm_kernel<<<kB, 256, 0, stream>>>(e_ws, W_f, b_f, W_i, b_i, W_c, b_c,
                                      W_o, b_o, W_out, b_out, out);
}

// Round 2
// 2593.342 us; speedup vs baseline: 1.1182x; 1.1182x over previous
//
#include <hip/hip_runtime.h>
#include <stdint.h>

namespace {
constexpr int kB = 64, kT = 4096, kDin = 64, kDe = 24, kH = 128;
constexpr int kChunk = 256;              // e-steps staged per LDS chunk
constexpr int kNChunk = kT / kChunk;     // 16
constexpr int kEB = kChunk * 12;         // uints per e chunk buffer (3072)
constexpr int kE0 = 128;                 // smem uint offset of e chunks (after 2x h buffers)

typedef __attribute__((ext_vector_type(2))) _Float16 half2_t;
union H2U { uint32_t u; half2_t h; _Float16 s[2]; };

__device__ __forceinline__ float rcp_fast(float x){
#if __has_builtin(__builtin_amdgcn_rcpf)
  return __builtin_amdgcn_rcpf(x);
#else
  return 1.0f / x;
#endif
}
__device__ __forceinline__ float sigmoid_f(float x){
  return rcp_fast(1.0f + __expf(-x));
}
__device__ __forceinline__ float tanh_f(float x){
  return 1.0f - 2.0f * rcp_fast(1.0f + __expf(2.0f * x));
}
__device__ __forceinline__ float dot2acc(uint32_t a, uint32_t b, float c){
  H2U ua; ua.u = a; H2U ub; ub.u = b;
#if __has_builtin(__builtin_amdgcn_fdot2)
  return __builtin_amdgcn_fdot2(ua.h, ub.h, c, false);
#else
  return c + (float)ua.s[0] * (float)ub.s[0] + (float)ua.s[1] * (float)ub.s[1];
#endif
}
__device__ __forceinline__ uint32_t pack2(float lo, float hi){
  H2U u; u.s[0] = (_Float16)lo; u.s[1] = (_Float16)hi; return u.u;
}
} // namespace

// Kernel 1 (parallel): e[b,t,:] = sigmoid(x[b,t,:] @ W_emb + b_emb) packed f16.
__global__ __launch_bounds__(256) void emb_kernel(
    const float* __restrict__ x, const float* __restrict__ W,
    const float* __restrict__ bias, uint32_t* __restrict__ e_out)
{
  int r = blockIdx.x * blockDim.x + threadIdx.x;
  if (r >= kB * kT) return;
  const float4* xr = (const float4*)(x + (size_t)r * kDin);
  float acc[kDe];
#pragma unroll
  for (int k = 0; k < kDe; ++k) acc[k] = bias[k];
#pragma unroll 4
  for (int d4 = 0; d4 < kDin / 4; ++d4){
    float4 xv = xr[d4];
    const float* w0 = W + (size_t)(d4 * 4) * kDe;
#pragma unroll
    for (int k = 0; k < kDe; ++k) acc[k] += xv.x * w0[k];
#pragma unroll
    for (int k = 0; k < kDe; ++k) acc[k] += xv.y * w0[kDe + k];
#pragma unroll
    for (int k = 0; k < kDe; ++k) acc[k] += xv.z * w0[2 * kDe + k];
#pragma unroll
    for (int k = 0; k < kDe; ++k) acc[k] += xv.w * w0[3 * kDe + k];
  }
  uint32_t p[12];
#pragma unroll
  for (int k = 0; k < 12; ++k)
    p[k] = pack2(sigmoid_f(acc[2 * k]), sigmoid_f(acc[2 * k + 1]));
  uint4* dst = (uint4*)(e_out + (size_t)r * 12);
  dst[0] = make_uint4(p[0], p[1], p[2],  p[3]);
  dst[1] = make_uint4(p[4], p[5], p[6],  p[7]);
  dst[2] = make_uint4(p[8], p[9], p[10], p[11]);
}

// Kernel 2: one block per batch element, 256 threads (4 waves).
// Wave w owns hidden units j = w*32 + (lane&31). Lane pair (l, l^32) K-splits
// the 152-wide dots of unit j's 4 gate columns: half0 = z[0..79], half1 =
// z[80..151]; combined with shfl_xor(32). One barrier per step.
// z = [e(24); h(128)] as f16. e staged in 256-step double-buffered LDS chunks.
__global__ __launch_bounds__(256, 1) void lstm_kernel(
    const uint32_t* __restrict__ e_ws,
    const float* __restrict__ W_f, const float* __restrict__ b_f,
    const float* __restrict__ W_i, const float* __restrict__ b_i,
    const float* __restrict__ W_c, const float* __restrict__ b_c,
    const float* __restrict__ W_o, const float* __restrict__ b_o,
    const float* __restrict__ W_out, const float* __restrict__ b_out,
    float* __restrict__ out)
{
  // smem layout (uints): [0,64) h parity0 (128 f16) | [64,128) h parity1 |
  //                      [128,3200) e chunk buf0 | [3200,6272) e chunk buf1
  __shared__ __align__(16) uint32_t smem[kE0 + 2 * kEB];
  __shared__ float red[4];

  const int b  = blockIdx.x;
  const int t0 = threadIdx.x;
  const int w  = t0 >> 6;
  const int l  = t0 & 63;
  const int lh = l & 31;
  const int hi = l >> 5;           // which K-half this lane computes
  const int j  = w * 32 + lh;      // hidden unit / gate column owned

  // ---- per-lane q-read descriptors (10 x uint4 from LDS per step) ----
  // hi==0: q0..2 from e (offsets 0,4,8 uints), q3..9 from h (uints 0..27)
  //        -> z elems 0..79, 40 real weight pairs.
  // hi==1: q0..8 from h uints 28..63 (z elems 80..151, 36 pairs), q9 dummy.
  int qoff[10]; int qsel[10];      // qsel=1 -> e-chunk base, 0 -> h base
#pragma unroll
  for (int k = 0; k < 10; ++k){
    if (hi == 0){ qsel[k] = (k < 3); qoff[k] = (k < 3) ? k * 4 : (k - 3) * 4; }
    else        { qsel[k] = 0;       qoff[k] = (k < 9) ? 28 + k * 4 : 60; }
  }

  // ---- pack this lane's weight pairs (4 gates x 40 pairs) into registers ----
  uint32_t wF[40], wI[40], wG[40], wO[40];
#pragma unroll
  for (int p = 0; p < 40; ++p){
    int r0 = (hi == 0) ? 2 * p : 80 + 2 * p;
    bool valid = (hi == 0) || (p < 36);
    if (valid){
      wF[p] = pack2(W_f[r0 * kH + j], W_f[(r0 + 1) * kH + j]);
      wI[p] = pack2(W_i[r0 * kH + j], W_i[(r0 + 1) * kH + j]);
      wG[p] = pack2(W_c[r0 * kH + j], W_c[(r0 + 1) * kH + j]);
      wO[p] = pack2(W_o[r0 * kH + j], W_o[(r0 + 1) * kH + j]);
    } else { wF[p] = wI[p] = wG[p] = wO[p] = 0u; }
  }
  const float bF0 = (hi == 0) ? b_f[j] : 0.0f;
  const float bI0 = (hi == 0) ? b_i[j] : 0.0f;
  const float bG0 = (hi == 0) ? b_c[j] : 0.0f;
  const float bO0 = (hi == 0) ? b_o[j] : 0.0f;

  // ---- e chunk staging helpers ----
  const uint4* e_rows = (const uint4*)e_ws;   // 3 uint4 per (b,t) row
  uint4 pre0, pre1, pre2;
  const size_t bbase = (size_t)b * kT * 3;

  // chunk 0 -> ebuf0
  {
    const uint4* src = e_rows + bbase;
    pre0 = src[t0]; pre1 = src[t0 + 256]; pre2 = src[t0 + 512];
    uint4* dst = (uint4*)&smem[kE0];
    dst[t0] = pre0; dst[t0 + 256] = pre1; dst[t0 + 512] = pre2;
  }
  if (t0 < 64) smem[t0] = 0u;      // h(parity0) = 0
  float cst = 0.0f, h_last = 0.0f;
  __syncthreads();

#pragma unroll 1
  for (int cc = 0; cc < kNChunk; ++cc){
    const int ebi = cc & 1;
    if (cc + 1 < kNChunk){         // issue next chunk's loads (held in regs)
      const uint4* src = e_rows + bbase + (size_t)(cc + 1) * kChunk * 3;
      pre0 = src[t0]; pre1 = src[t0 + 256]; pre2 = src[t0 + 512];
    }
    const int ebase0 = kE0 + ebi * kEB;

#pragma unroll 1
    for (int s = 0; s < kChunk; ++s){
      const int t   = cc * kChunk + s;
      const int cur = t & 1, nxt = cur ^ 1;
      const int eb  = ebase0 + s * 12;
      const int hb  = cur * 64;

      uint4 q[10];
#pragma unroll
      for (int k = 0; k < 10; ++k){
        int idx = (qsel[k] ? eb : hb) + qoff[k];
        q[k] = *(const uint4*)&smem[idx];
      }
      float aF = bF0, aI = bI0, aG = bG0, aO = bO0;
#pragma unroll
      for (int k = 0; k < 10; ++k){
        uint4 qq = q[k];
        aF = dot2acc(qq.x, wF[4*k+0], aF); aI = dot2acc(qq.x, wI[4*k+0], aI);
        aG = dot2acc(qq.x, wG[4*k+0], aG); aO = dot2acc(qq.x, wO[4*k+0], aO);
        aF = dot2acc(qq.y, wF[4*k+1], aF); aI = dot2acc(qq.y, wI[4*k+1], aI);
        aG = dot2acc(qq.y, wG[4*k+1], aG); aO = dot2acc(qq.y, wO[4*k+1], aO);
        aF = dot2acc(qq.z, wF[4*k+2], aF); aI = dot2acc(qq.z, wI[4*k+2], aI);
        aG = dot2acc(qq.z, wG[4*k+2], aG); aO = dot2acc(qq.z, wO[4*k+2], aO);
        aF = dot2acc(qq.w, wF[4*k+3], aF); aI = dot2acc(qq.w, wI[4*k+3], aI);
        aG = dot2acc(qq.w, wG[4*k+3], aG); aO = dot2acc(qq.w, wO[4*k+3], aO);
      }
      // combine K-halves (lane l gets l^32's partial)
      aF += __shfl_xor(aF, 32, 64);
      aI += __shfl_xor(aI, 32, 64);
      aG += __shfl_xor(aG, 32, 64);
      aO += __shfl_xor(aO, 32, 64);

      if (hi == 0){
        float f  = sigmoid_f(aF);
        float ig = sigmoid_f(aI);
        float gg = tanh_f(aG);
        float og = sigmoid_f(aO);
        cst = cst * f + ig * gg;
        h_last = tanh_f(cst) * og;
        ((_Float16*)&smem[nxt * 64])[j] = (_Float16)h_last;
      }
      __syncthreads();
    }

    if (cc + 1 < kNChunk){         // commit next chunk into the other buffer
      uint4* dst = (uint4*)&smem[kE0 + (ebi ^ 1) * kEB];
      dst[t0] = pre0; dst[t0 + 256] = pre1; dst[t0 + 512] = pre2;
      __syncthreads();
    }
  }

  // ---- epilogue: out[b] = sigmoid(h_T @ W_out + b_out) ----
  float partial = (hi == 0) ? h_last * W_out[j] : 0.0f;
#pragma unroll
  for (int off = 1; off <= 32; off <<= 1) partial += __shfl_xor(partial, off, 64);
  if (l == 0) red[w] = partial;
  __syncthreads();
  if (t0 == 0)
    out[b] = sigmoid_f(red[0] + red[1] + red[2] + red[3] + b_out[0]);
}

extern "C" void kernel_launch(void* const* d_in, const int* in_sizes, int n_in,
                              void* d_out, int out_size, void* d_ws, size_t ws_size,
                              hipStream_t stream){
  const float* x     = (const float*)d_in[0];
  const float* W_emb = (const float*)d_in[1];
  const float* b_emb = (const float*)d_in[2];
  const float* W_f   = (const float*)d_in[3];
  const float* b_f   = (const float*)d_in[4];
  const float* W_i   = (const float*)d_in[5];
  const float* b_i   = (const float*)d_in[6];
  const float* W_c   = (const float*)d_in[7];
  const float* b_c   = (const float*)d_in[8];
  const float* W_o   = (const float*)d_in[9];
  const float* b_o   = (const float*)d_in[10];
  const float* W_out = (const float*)d_in[11];
  const float* b_out = (const float*)d_in[12];
  float* out = (float*)d_out;
  uint32_t* e_ws = (uint32_t*)d_ws;    // B*T*12*4 = 12.6 MB

  const int rows = kB * kT;
  emb_kernel<<<(rows + 255) / 256, 256, 0, stream>>>(x, W_emb, b_emb, e_ws);
  lstm_kernel<<<kB, 256, 0, stream>>>(e_ws, W_f, b_f, W_i, b_i, W_c, b_c,
                                      W_o, b_o, W_out, b_out, out);
}